// Round 1
// 653.664 us; speedup vs baseline: 1.0811x; 1.0811x over previous
//
#include <hip/hip_runtime.h>

// ---------------------------------------------------------------------------
// CrossModalAttention: RoPE -> Q/K/V proj -> softmax(QK^T/sqrt(H)) V -> out proj
// B=4, S=2048, H=2048. All contractions via bf16 MFMA 16x16x32 (fp32 acc).
// R1: XOR-swizzled LDS staging -> 0 bank conflicts.
// R2: fused elementwise, transposed V-proj epilogue, bf16 score carry.
// R3: 256x256 8-phase GEMM (HK schedule in plain HIP): 8 waves, BK=64,
//     double-buffered 128KiB LDS in 16KB units, counted vmcnt(4) at phases
//     4/8 only (loads stay in flight across barriers), setprio around MFMA.
// ---------------------------------------------------------------------------

typedef __bf16 bf16_t;
typedef bf16_t bf16x8 __attribute__((ext_vector_type(8)));
typedef bf16_t bf16x4 __attribute__((ext_vector_type(4)));
typedef float  f32x4  __attribute__((ext_vector_type(4)));

#define BDIM 4
#define SDIM 2048
#define HDIM 2048

__device__ __forceinline__ void async_copy16(const bf16_t* g, bf16_t* l) {
  __builtin_amdgcn_global_load_lds(
      (__attribute__((address_space(1))) const void*)g,
      (__attribute__((address_space(3))) void*)l,
      16, 0, 0);
}

// ---------------------------------------------------------------------------
// Fused prep: RoPE on q,k + cast v. One thread per (row, pair j/j+1024).
// ---------------------------------------------------------------------------
__global__ __launch_bounds__(256) void prep_kernel(
    const float* __restrict__ q, const float* __restrict__ k,
    const float* __restrict__ v,
    bf16_t* __restrict__ qr, bf16_t* __restrict__ kr, bf16_t* __restrict__ vb) {
  const int i = blockIdx.x * 256 + threadIdx.x;   // 0 .. B*S*1024-1
  const int j = i & 1023;
  const int row = i >> 10;                        // 0..8191
  const int s = row & (SDIM - 1);
  const float invf = exp2f(-(float)j * 0.012976281620653759f); // log2(1e4)/1024
  const float f = (float)s * invf;
  float sn, cs;
  sincosf(f, &sn, &cs);
  const long base = (long)row * HDIM;
  const float q1 = q[base + j], q2 = q[base + j + 1024];
  const float k1 = k[base + j], k2 = k[base + j + 1024];
  qr[base + j]        = (bf16_t)(q1 * cs - q2 * sn);
  qr[base + j + 1024] = (bf16_t)(q2 * cs + q1 * sn);
  kr[base + j]        = (bf16_t)(k1 * cs - k2 * sn);
  kr[base + j + 1024] = (bf16_t)(k2 * cs + k1 * sn);
  vb[base + j]        = (bf16_t)v[base + j];
  vb[base + j + 1024] = (bf16_t)v[base + j + 1024];
}

// ---------------------------------------------------------------------------
// Cast all 4 weight matrices fp32->bf16 in one launch. 8 elems/thread.
// ---------------------------------------------------------------------------
__global__ __launch_bounds__(256) void wcast_kernel(
    const float* __restrict__ w0, const float* __restrict__ w1,
    const float* __restrict__ w2, const float* __restrict__ w3,
    bf16_t* __restrict__ dst) {
  const int wsel = blockIdx.y;
  const float* src = wsel == 0 ? w0 : wsel == 1 ? w1 : wsel == 2 ? w2 : w3;
  const long i = (long)(blockIdx.x * 256 + threadIdx.x) * 8;
  const float4 a = *(const float4*)&src[i];
  const float4 b = *(const float4*)&src[i + 4];
  bf16x8 o;
  o[0] = (bf16_t)a.x; o[1] = (bf16_t)a.y; o[2] = (bf16_t)a.z; o[3] = (bf16_t)a.w;
  o[4] = (bf16_t)b.x; o[5] = (bf16_t)b.y; o[6] = (bf16_t)b.z; o[7] = (bf16_t)b.w;
  *(bf16x8*)&dst[(long)wsel * HDIM * HDIM + i] = o;
}

// ---------------------------------------------------------------------------
// Stage one 16KB unit of a [256][64]-bf16 LDS tile via global_load_lds.
// LDS(row, chunk j) = global(row, chunk j ^ (row&7)), 16B chunks (swizzle
// encoded in the per-lane GLOBAL address; LDS dest stays linear).
// A units (half 0/1): row-groups {0..7,16..23} / {8..15,24..31}  (M-halves)
// B units (half 0/1): row-groups {0..3,8..11,16..19,24..27} / +4 (N-halves)
// Each of 8 waves issues 2 loads (1KB each) -> 16KB.
// ---------------------------------------------------------------------------
__device__ __forceinline__ void stage_A_unit(const bf16_t* __restrict__ G, int K,
                                             int kq, bf16_t* L, int half,
                                             int wave, int rl, int ccs) {
#pragma unroll
  for (int c = 0; c < 2; ++c) {
    const int idx = c * 8 + wave;
    const int g = (idx >> 3) * 16 + (idx & 7) + half * 8;
    async_copy16(G + (long)(g * 8 + rl) * K + kq + ccs, L + g * 512);
  }
}
__device__ __forceinline__ void stage_B_unit(const bf16_t* __restrict__ G, int K,
                                             int kq, bf16_t* L, int half,
                                             int wave, int rl, int ccs) {
#pragma unroll
  for (int c = 0; c < 2; ++c) {
    const int idx = c * 8 + wave;
    const int g = (idx >> 2) * 8 + (idx & 3) + half * 4;
    async_copy16(G + (long)(g * 8 + rl) * K + kq + ccs, L + g * 512);
  }
}

// ---------------------------------------------------------------------------
// NT GEMM: C[M,N] = alpha * A[M,K] * Bt[N,K]^T + bias. Batched via blockIdx.z.
// 256x256 tile, BK=64, 512 threads = 8 waves (2M x 4N); per-wave C = 128x64.
// 8-phase K-loop over 2 K-tiles/iter; quadrant (MH,NH) per phase, A frags
// register-reused across the NH pair. Counted vmcnt(4) at phases 4 & 8 only.
// Requires: M,N % 256 == 0, K % 128 == 0, K power of two (wrap prefetch).
// OMODE: 0 bf16 row-major, 1 fp32 row-major, 2 bf16 transposed per batch.
// ---------------------------------------------------------------------------
template <int OMODE>
__global__ __launch_bounds__(512, 2) void gemm_bt(
    const bf16_t* __restrict__ A, const bf16_t* __restrict__ Bt,
    void* __restrict__ Cv, const float* __restrict__ bias,
    int M, int N, int K, float alpha,
    long sA, long sB, long sC) {
  __shared__ __align__(16) bf16_t lds[4 * 16384];   // 128 KiB
  bf16_t* As0 = lds;
  bf16_t* Bs0 = lds + 16384;
  bf16_t* As1 = lds + 32768;
  bf16_t* Bs1 = lds + 49152;
  const int z = blockIdx.z;
  A  += (long)z * sA;
  Bt += (long)z * sB;
  const int tid  = threadIdx.x;
  const int lane = tid & 63;
  const int wave = tid >> 6;
  const int wm = (wave >> 2) * 128;   // wave row offset in tile (M)
  const int wn = (wave & 3) * 64;     // wave col offset in tile (N)
  const int m0 = blockIdx.y * 256;
  const int n0 = blockIdx.x * 256;
  const int lrow = lane & 15;
  const int quad = lane >> 4;
  const int rl  = lane >> 3;                 // staging row within 8-row group
  const int ccs = ((lane & 7) ^ rl) * 8;     // pre-swizzled global column

  const bf16_t* Ab = A  + (long)m0 * K;
  const bf16_t* Bb = Bt + (long)n0 * K;

  f32x4 acc[8][4] = {};

#define DS_A(AS, MH)                                                         \
  _Pragma("unroll") for (int ks = 0; ks < 2; ++ks) {                         \
    const int cg = ks * 4 + quad;                                            \
    _Pragma("unroll") for (int t = 0; t < 4; ++t) {                          \
      const int r = wm + ((MH) * 4 + t) * 16 + lrow;                         \
      af[t][ks] = *(const bf16x8*)&(AS)[r * 64 + ((cg ^ (r & 7)) * 8)];      \
    }                                                                        \
  }
#define DS_B(BS, NH)                                                         \
  _Pragma("unroll") for (int ks = 0; ks < 2; ++ks) {                         \
    const int cg = ks * 4 + quad;                                            \
    _Pragma("unroll") for (int u = 0; u < 2; ++u) {                          \
      const int r = wn + ((NH) * 2 + u) * 16 + lrow;                         \
      bfr[u][ks] = *(const bf16x8*)&(BS)[r * 64 + ((cg ^ (r & 7)) * 8)];     \
    }                                                                        \
  }
#define MFMA_Q(MH, NH)                                                       \
  __builtin_amdgcn_s_barrier();                                              \
  asm volatile("s_waitcnt lgkmcnt(0)" ::: "memory");                         \
  __builtin_amdgcn_s_setprio(1);                                             \
  _Pragma("unroll") for (int ks = 0; ks < 2; ++ks)                           \
    _Pragma("unroll") for (int t = 0; t < 4; ++t)                            \
      _Pragma("unroll") for (int u = 0; u < 2; ++u)                          \
        acc[(MH) * 4 + t][(NH) * 2 + u] =                                    \
            __builtin_amdgcn_mfma_f32_16x16x32_bf16(                         \
                af[t][ks], bfr[u][ks], acc[(MH) * 4 + t][(NH) * 2 + u],      \
                0, 0, 0);                                                    \
  __builtin_amdgcn_s_setprio(0);
#define VM_WAIT4 asm volatile("s_waitcnt vmcnt(4)" ::: "memory");
#define ENDBAR   __builtin_amdgcn_s_barrier();

  // prologue: tile0 (all 4 units) + tile1 {A.U0, B.U2}; retire tile0 (8 of 12)
  stage_A_unit(Ab, K, 0,  As0, 0, wave, rl, ccs);
  stage_A_unit(Ab, K, 0,  As0, 1, wave, rl, ccs);
  stage_B_unit(Bb, K, 0,  Bs0, 0, wave, rl, ccs);
  stage_B_unit(Bb, K, 0,  Bs0, 1, wave, rl, ccs);
  stage_A_unit(Ab, K, 64, As1, 0, wave, rl, ccs);
  stage_B_unit(Bb, K, 64, Bs1, 0, wave, rl, ccs);
  asm volatile("s_waitcnt vmcnt(4)" ::: "memory");
  __builtin_amdgcn_s_barrier();

  const int Km = K - 1;                 // K is a power of two
  for (int k0 = 0; k0 < K; k0 += 128) {
    bf16x8 af[4][2], bfr[2][2];
    const int kA = k0 + 64;             // tile t1 (always valid)
    const int kB = (k0 + 128) & Km;     // tile t2 (wraps harmlessly on last iter)
    const int kC = (k0 + 192) & Km;     // tile t3
    // ph1: buf0 quadrant (0,0); stage buf1.A.U1 (t1)
    DS_A(As0, 0) DS_B(Bs0, 0)
    stage_A_unit(Ab, K, kA, As1, 1, wave, rl, ccs);
    MFMA_Q(0, 0) ENDBAR
    // ph2: (0,1) [A frags reused]; stage buf1.B.U3 (t1)
    DS_B(Bs0, 1)
    stage_B_unit(Bb, K, kA, Bs1, 1, wave, rl, ccs);
    MFMA_Q(0, 1) ENDBAR
    // ph3: (1,0); stage buf0.A.U0 (t2) [slot last read ph1]
    DS_A(As0, 1) DS_B(Bs0, 0)
    stage_A_unit(Ab, K, kB, As0, 0, wave, rl, ccs);
    MFMA_Q(1, 0) ENDBAR
    // ph4: (1,1); stage buf0.B.U2 (t2); counted drain
    DS_B(Bs0, 1)
    stage_B_unit(Bb, K, kB, Bs0, 0, wave, rl, ccs);
    MFMA_Q(1, 1) VM_WAIT4 ENDBAR
    // ph5: buf1 quadrant (0,0); stage buf0.A.U1 (t2)
    DS_A(As1, 0) DS_B(Bs1, 0)
    stage_A_unit(Ab, K, kB, As0, 1, wave, rl, ccs);
    MFMA_Q(0, 0) ENDBAR
    // ph6: (0,1); stage buf0.B.U3 (t2)
    DS_B(Bs1, 1)
    stage_B_unit(Bb, K, kB, Bs0, 1, wave, rl, ccs);
    MFMA_Q(0, 1) ENDBAR
    // ph7: (1,0); stage buf1.A.U0 (t3)
    DS_A(As1, 1) DS_B(Bs1, 0)
    stage_A_unit(Ab, K, kC, As1, 0, wave, rl, ccs);
    MFMA_Q(1, 0) ENDBAR
    // ph8: (1,1); stage buf1.B.U2 (t3); counted drain
    DS_B(Bs1, 1)
    stage_B_unit(Bb, K, kC, Bs1, 0, wave, rl, ccs);
    MFMA_Q(1, 1) VM_WAIT4 ENDBAR
  }
#undef DS_A
#undef DS_B
#undef MFMA_Q
#undef VM_WAIT4
#undef ENDBAR

  // epilogue: D[row=quad*4+r][col=lane&15] per 16x16 tile (HW-verified layout)
#pragma unroll
  for (int mt = 0; mt < 8; ++mt) {
#pragma unroll
    for (int nt = 0; nt < 4; ++nt) {
      const int col = n0 + wn + nt * 16 + lrow;
      const float bv = bias ? bias[col] : 0.0f;
      if (OMODE == 2) {
        // transposed store: 4 consecutive s per lane -> one 8B store
        const int row0 = m0 + wm + mt * 16 + quad * 4;
        const int b = row0 >> 11;            // SDIM = 2048
        const int s = row0 & (SDIM - 1);
        bf16x4 o;
#pragma unroll
        for (int r = 0; r < 4; ++r) o[r] = (bf16_t)(acc[mt][nt][r] + bv);
        *(bf16x4*)&((bf16_t*)Cv)[(long)b * SDIM * HDIM + (long)col * SDIM + s] = o;
      } else {
#pragma unroll
        for (int r = 0; r < 4; ++r) {
          const int row = m0 + wm + mt * 16 + quad * 4 + r;
          const float v = acc[mt][nt][r] * alpha + bv;
          if (OMODE == 1)
            ((float*)Cv)[(long)z * sC + (long)row * N + col] = v;
          else
            ((bf16_t*)Cv)[(long)z * sC + (long)row * N + col] = (bf16_t)v;
        }
      }
    }
  }
}

// ---------------------------------------------------------------------------
// Row softmax: bf16 scores [rows,2048] -> bf16 probs. 256 thr/row, 8 elems/thr.
// ---------------------------------------------------------------------------
__global__ __launch_bounds__(256) void softmax_kernel(
    const bf16_t* __restrict__ Sc, bf16_t* __restrict__ P) {
  const long row = blockIdx.x;
  const bf16_t* src = Sc + row * SDIM;
  bf16_t* dst = P + row * SDIM;
  const int tid = threadIdx.x;
  const bf16x8 in = *(const bf16x8*)&src[tid * 8];
  float x[8];
#pragma unroll
  for (int t = 0; t < 8; ++t) x[t] = (float)in[t];
  float m = x[0];
#pragma unroll
  for (int t = 1; t < 8; ++t) m = fmaxf(m, x[t]);
#pragma unroll
  for (int off = 32; off; off >>= 1) m = fmaxf(m, __shfl_xor(m, off));
  __shared__ float redm[4], reds[4];
  const int wave = tid >> 6, lane = tid & 63;
  if (lane == 0) redm[wave] = m;
  __syncthreads();
  m = fmaxf(fmaxf(redm[0], redm[1]), fmaxf(redm[2], redm[3]));
  float s = 0.0f;
#pragma unroll
  for (int t = 0; t < 8; ++t) { x[t] = __expf(x[t] - m); s += x[t]; }
#pragma unroll
  for (int off = 32; off; off >>= 1) s += __shfl_xor(s, off);
  if (lane == 0) reds[wave] = s;
  __syncthreads();
  s = reds[0] + reds[1] + reds[2] + reds[3];
  const float inv = 1.0f / s;
  bf16x8 o;
#pragma unroll
  for (int t = 0; t < 8; ++t) o[t] = (bf16_t)(x[t] * inv);
  *(bf16x8*)&dst[tid * 8] = o;
}

// ---------------------------------------------------------------------------
extern "C" void kernel_launch(void* const* d_in, const int* in_sizes, int n_in,
                              void* d_out, int out_size, void* d_ws, size_t ws_size,
                              hipStream_t stream) {
  const float* q_in = (const float*)d_in[0];
  const float* k_in = (const float*)d_in[1];
  const float* v_in = (const float*)d_in[2];
  const float* Wq = (const float*)d_in[3];
  const float* bq = (const float*)d_in[4];
  const float* Wk = (const float*)d_in[5];
  const float* bk = (const float*)d_in[6];
  const float* Wv = (const float*)d_in[7];
  const float* bv = (const float*)d_in[8];
  const float* Wo = (const float*)d_in[9];
  const float* bo = (const float*)d_in[10];
  float* out = (float*)d_out;

  const size_t ELE  = (size_t)BDIM * SDIM * HDIM;   // 16,777,216
  const size_t WELE = (size_t)HDIM * HDIM;          // 4,194,304
  const size_t SEG  = ELE * 2;                      // 33,554,432 B per bf16 [B,S,H]

  uint8_t* w = (uint8_t*)d_ws;
  bf16_t* qr  = (bf16_t*)(w + 0 * SEG);
  bf16_t* kr  = (bf16_t*)(w + 1 * SEG);
  bf16_t* vb  = (bf16_t*)(w + 2 * SEG);
  bf16_t* Wb  = (bf16_t*)(w + 3 * SEG);   // Wq,Wk,Wv,Wo bf16 consecutive
  bf16_t* qp  = (bf16_t*)(w + 4 * SEG);
  bf16_t* kp  = (bf16_t*)(w + 5 * SEG);
  bf16_t* vpT = (bf16_t*)(w + 6 * SEG);   // V-proj writes transposed here
  // aliases (regions dead by the time they're written):
  bf16_t* scores = (bf16_t*)(w + 0 * SEG);  // over qr (dead after q-proj)
  bf16_t* probs  = (bf16_t*)(w + 2 * SEG);  // over vb (dead after v-proj)
  bf16_t* ctx    = (bf16_t*)(w + 1 * SEG);  // over kr (dead after k-proj)

  bf16_t* Wqb = Wb + 0 * WELE;
  bf16_t* Wkb = Wb + 1 * WELE;
  bf16_t* Wvb = Wb + 2 * WELE;
  bf16_t* Wob = Wb + 3 * WELE;

  const dim3 blk(256);
  const dim3 gblk(512);                // 8 waves for the 256^2 GEMM
  const long SH = (long)SDIM * HDIM;   // per-batch activation stride (elems)
  const long SS = (long)SDIM * SDIM;   // per-batch score stride (elems)

  // 1. RoPE q,k + cast v -> bf16
  prep_kernel<<<dim3(ELE / 2 / 256), blk, 0, stream>>>(q_in, k_in, v_in, qr, kr, vb);
  // 2. weight casts (one launch)
  wcast_kernel<<<dim3(WELE / 8 / 256, 4), blk, 0, stream>>>(Wq, Wk, Wv, Wo, Wb);
  // 3-5. projections: [8192,2048] x [2048,2048]^T + bias  (grid = 256 = 1 blk/CU)
  gemm_bt<0><<<dim3(8, 32, 1), gblk, 0, stream>>>(qr, Wqb, qp, bq,
      BDIM * SDIM, HDIM, HDIM, 1.0f, 0, 0, 0);
  gemm_bt<0><<<dim3(8, 32, 1), gblk, 0, stream>>>(kr, Wkb, kp, bk,
      BDIM * SDIM, HDIM, HDIM, 1.0f, 0, 0, 0);
  gemm_bt<2><<<dim3(8, 32, 1), gblk, 0, stream>>>(vb, Wvb, vpT, bv,
      BDIM * SDIM, HDIM, HDIM, 1.0f, 0, 0, 0);   // writes vpT[b][h][s]
  // 6. scores = qp kp^T / sqrt(H)  (bf16 out, batched)
  gemm_bt<0><<<dim3(8, 8, BDIM), gblk, 0, stream>>>(qp, kp, scores, nullptr,
      SDIM, SDIM, HDIM, 0.022097086912079612f, SH, SH, SS);
  // 7. softmax rows -> bf16 probs
  softmax_kernel<<<dim3(BDIM * SDIM), blk, 0, stream>>>(scores, probs);
  // 8. ctx = probs @ vp  ==  NT(probs, vpT)
  gemm_bt<0><<<dim3(8, 8, BDIM), gblk, 0, stream>>>(probs, vpT, ctx, nullptr,
      SDIM, HDIM, SDIM, 1.0f, SS, SH, SH);
  // 9. out = ctx Wo^T + bo  (fp32 -> d_out)
  gemm_bt<1><<<dim3(8, 32, 1), gblk, 0, stream>>>(ctx, Wob, out, bo,
      BDIM * SDIM, HDIM, HDIM, 1.0f, 0, 0, 0);
}